// Round 13
// baseline (498.569 us; speedup 1.0000x reference)
//
#include <hip/hip_runtime.h>
#include <hip/hip_bf16.h>
#include <stdint.h>
#include <math.h>

// TreeLSTM on MI355X — v13: FRAGMENT-PACKED inter-level h.
// Root cause of the 112-143us plateau (7 variants): A-fragment accesses were
// strided (64 lines x 16B used) regardless of pipeline style. Fix: we produce
// h ourselves, so store it in MFMA-A-fragment order:
//   hP[t][ks][mt][lane][8], elem (m=mt*16+(lane&15), k=ks*32+(lane>>4)*8+e)
//   = h_cat[parent = t*64+m][k]  (k<256: left child, else right child)
// -> every K-loop A-frag load is ONE contiguous 1KB (16 full lines). BtP was
// already packed -> same. Level kernel: NO LDS, NO barriers, ~16 waves/CU;
// wave = 64 rows x 1 ct x 5 gates, 20 MFMA per K32-chunk. c stored as
// cc[parent][512] (epilogue's native read shape). XCD-affine swizzle kept.

typedef __bf16 bf16x8 __attribute__((ext_vector_type(8)));
typedef float  f32x4  __attribute__((ext_vector_type(4)));

__device__ __forceinline__ float sigf(float x) { return 1.f / (1.f + __expf(-x)); }
__device__ __forceinline__ float tanhfast(float x) {
    return 1.f - 2.f / (__expf(2.f * x) + 1.f);   // stable at |x| large
}

__global__ void xg_prep(const float* __restrict__ emb, const float* __restrict__ W,
                        const float* __restrict__ bW, float* __restrict__ xg) {
    int g = blockIdx.x >> 6, v = blockIdx.x & 63, k = threadIdx.x;
    __shared__ float e[256];
    e[k] = emb[v * 256 + k];
    __syncthreads();
    float s = bW[g * 256 + k];
    const float* Wg = W + g * 65536 + k;
#pragma unroll 4
    for (int i = 0; i < 256; i++) s += e[i] * Wg[i * 256];
    xg[(g * 64 + v) * 256 + k] = s;
}

// Pack U into MFMA-fragment order: BtP[g][ct][ks][lane][e], e<8
// value = Ucat[g][col=ct*16+(lane&15)][k=ks*32+(lane>>4)*8+e]
// Ucat[g][col][k] = U[g][k<256?0:1][k&255][col]
__global__ void bt_prep(const float* __restrict__ U, __bf16* __restrict__ BtP) {
    int t = blockIdx.x * 256 + threadIdx.x;     // < 81920
    int g    = t >> 14;
    int r    = t & 16383;
    int ct   = r >> 10;
    int ks   = (r >> 6) & 15;
    int lane = t & 63;
    int lr = lane & 15, q = lane >> 4;
    int col = ct * 16 + lr;
    int kbase = ks * 32 + q * 8;
    bf16x8 v8;
#pragma unroll
    for (int e = 0; e < 8; e++) {
        int k = kbase + e;
        int s = k >> 8, kk = k & 255;
        v8[e] = (__bf16)U[((g * 2 + s) * 256 + kk) * 256 + col];
    }
    *(bf16x8*)(BtP + (long)t * 8) = v8;
}

// Leaf: writes hP (packed, coalesced 16B/thread) + cc (concat row-major).
// Thread gidx handles packed elems [gidx*8, gidx*8+8):
//   lane=(gidx&63), mt=(gidx>>6)&3, ks=(gidx>>8)&15, t=gidx>>12
//   m=mt*16+(lane&15), kb=ks*32+(lane>>4)*8 ; child r=(t*64+m)*2+(kb>=256)
__global__ void leaf_kernel(const int* __restrict__ ids, const float* __restrict__ xg,
                            __bf16* __restrict__ hP, __bf16* __restrict__ cc) {
    int gidx = blockIdx.x * 256 + threadIdx.x;    // < 2,097,152
    int lane = gidx & 63;
    int mt   = (gidx >> 6) & 3;
    int ks   = (gidx >> 8) & 15;
    int t    = gidx >> 12;
    int m  = mt * 16 + (lane & 15);
    int kb = ks * 32 + (lane >> 4) * 8;
    int parent = t * 64 + m;
    int r  = parent * 2 + (kb >= 256 ? 1 : 0);
    int col = kb & 255;
    int b = r >> 10, j = r & 1023;
    int id = ids[b * 2046 + 1022 + j];
    const float* x1p = xg + (64  + id) * 256 + col;
    const float* x2p = xg + (128 + id) * 256 + col;
    const float* x3p = xg + (192 + id) * 256 + col;
    bf16x8 hv8, cv8;
#pragma unroll
    for (int e = 0; e < 8; e++) {
        float ig = sigf(x1p[e]);
        float og = sigf(x2p[e]);
        float ug = tanhfast(x3p[e]);
        float cv = ig * ug;
        float hv = og * tanhfast(cv);
        hv8[e] = (__bf16)hv;
        cv8[e] = (__bf16)cv;
    }
    *(bf16x8*)(hP + (long)gidx * 8) = hv8;
    *(bf16x8*)(cc + (long)parent * 512 + kb) = cv8;
}

// Block = 256 thr = 4 waves; wave = 64 rows x 1 ct (16 cols) x 5 gates.
// Grid = RG*16 blocks (RG = M/256 row-groups), XCD-affine ct-fast swizzle.
// A from hP (packed, contiguous 1KB frags); B from BtP (packed, contiguous).
// No LDS, no barriers.
__global__ __launch_bounds__(256) void level_kernel(
    const __bf16* __restrict__ hP_in, const __bf16* __restrict__ cc_in,
    const __bf16* __restrict__ BtP, const float* __restrict__ xg,
    const int* __restrict__ ids, __bf16* __restrict__ hP_out,
    __bf16* __restrict__ cc_out, float* __restrict__ rh_out, int lev, int M, int RG) {
    const int gid = blockIdx.x;
    int rg, ct;
    if ((RG & 7) == 0) {
        int xcd = gid & 7;
        int tt  = gid >> 3;
        ct = tt & 15;
        rg = ((tt >> 4) << 3) | xcd;
    } else {
        rg = gid >> 4;
        ct = gid & 15;
    }
    const int wave = threadIdx.x >> 6;
    const int lane = threadIdx.x & 63;
    const int lr = lane & 15, q = lane >> 4;
    const long wrow = (long)rg * 256 + wave * 64;
    if (wrow >= M) return;

    // Packed A tile base for this wave's 64 rows; frag (ks,mt) at +(ks*4+mt)*512.
    const __bf16* Ap = hP_in + (wrow >> 6) * 32768 + lane * 8;
    // Packed B base for this ct; frag (g,ks) at +(g*16 + ks... ) see bt_prep:
    // BtP[((g*16+ct)*16 + ks)*512 + lane*8]
    const __bf16* Bp = BtP + (long)ct * 8192 + lane * 8;   // + g*131072 + ks*512

    f32x4 acc[5][4];
#pragma unroll
    for (int g2 = 0; g2 < 5; g2++)
#pragma unroll
        for (int mt = 0; mt < 4; mt++) acc[g2][mt] = (f32x4){0.f, 0.f, 0.f, 0.f};

    bf16x8 aa[2][4], bb[2][5];
#pragma unroll
    for (int mt = 0; mt < 4; mt++) aa[0][mt] = *(const bf16x8*)(Ap + mt * 512);
#pragma unroll
    for (int g2 = 0; g2 < 5; g2++) bb[0][g2] = *(const bf16x8*)(Bp + g2 * 131072);

#pragma unroll
    for (int s = 0; s < 16; s++) {
        const int cur = s & 1, nxt = cur ^ 1;
        if (s + 1 < 16) {
#pragma unroll
            for (int mt = 0; mt < 4; mt++)
                aa[nxt][mt] = *(const bf16x8*)(Ap + ((s + 1) * 4 + mt) * 512);
#pragma unroll
            for (int g2 = 0; g2 < 5; g2++)
                bb[nxt][g2] = *(const bf16x8*)(Bp + g2 * 131072 + (s + 1) * 512);
        }
#pragma unroll
        for (int g2 = 0; g2 < 5; g2++)
#pragma unroll
            for (int mt = 0; mt < 4; mt++)
                acc[g2][mt] = __builtin_amdgcn_mfma_f32_16x16x32_bf16(
                    aa[cur][mt], bb[cur][g2], acc[g2][mt], 0, 0, 0);
    }

    // ---- Epilogue. C layout: col = lane&15 (gcol), row = q*4+v (+16*mt). ----
    const int n = 1 << lev;
    const int gcol = ct * 16 + lr;
    int idv[4][4];
    float clv[4][4], crv[4][4];
#pragma unroll
    for (int mt = 0; mt < 4; mt++)
#pragma unroll
        for (int v = 0; v < 4; v++) {
            long grow = wrow + mt * 16 + q * 4 + v;
            int b = (int)(grow >> lev);
            int j = (int)(grow & (n - 1));
            idv[mt][v] = ids[b * 2046 + (n - 2) + j];
            clv[mt][v] = (float)cc_in[grow * 512 + gcol];
            crv[mt][v] = (float)cc_in[grow * 512 + 256 + gcol];
        }
#pragma unroll
    for (int mt = 0; mt < 4; mt++) {
#pragma unroll
        for (int v = 0; v < 4; v++) {
            long grow = wrow + mt * 16 + q * 4 + v;
            const float* xp = xg + idv[mt][v] * 256 + gcol;
            float fl = sigf(acc[0][mt][v] + xp[0]);          // f_l,f_r share xg[0]
            float fr = sigf(acc[1][mt][v] + xp[0]);
            float ig = sigf(acc[2][mt][v] + xp[16384]);      // xg[1]
            float og = sigf(acc[3][mt][v] + xp[32768]);      // xg[2]
            float ug = tanhfast(acc[4][mt][v] + xp[49152]);  // xg[3]
            float cv = ig * ug + fl * clv[mt][v] + fr * crv[mt][v];
            float hv = og * tanhfast(cv);
            long parent = grow >> 1;
            int  k = ((int)grow & 1) * 256 + gcol;
            if (rh_out) {
                rh_out[parent * 512 + k] = hv;               // lev1: root_hidden
            } else {
                cc_out[parent * 512 + k] = (__bf16)cv;
                // packed h: t=parent>>6, m=parent&63, ks=k>>5, q'=(k>>3)&3, e=k&7
                long t2 = parent >> 6;
                int  m2 = (int)parent & 63;
                int  ks2 = k >> 5, qp = (k >> 3) & 3, e2 = k & 7;
                long addr = t2 * 32768 + (long)ks2 * 2048 + (m2 >> 4) * 512 +
                            (qp * 16 + (m2 & 15)) * 8 + e2;
                hP_out[addr] = (__bf16)hv;
            }
        }
    }
}

__global__ void scores_kernel(const float* __restrict__ rh, const float* __restrict__ Ws,
                              const float* __restrict__ bs, float* __restrict__ out) {
    int b = blockIdx.x;
    int t = threadIdx.x >> 6, lane = threadIdx.x & 63;
    float s = 0.f;
    for (int i = lane; i < 512; i += 64) s += rh[b * 512 + i] * Ws[i * 3 + t];
    for (int o = 32; o > 0; o >>= 1) s += __shfl_down(s, o);
    if (lane == 0) out[b * 3 + t] = s + bs[t];
}

extern "C" void kernel_launch(void* const* d_in, const int* in_sizes, int n_in,
                              void* d_out, int out_size, void* d_ws, size_t ws_size,
                              hipStream_t stream) {
    const int*   ids = (const int*)  d_in[0];
    const float* emb = (const float*)d_in[1];
    const float* W   = (const float*)d_in[2];
    const float* bW  = (const float*)d_in[3];
    const float* U   = (const float*)d_in[4];
    const float* Ws  = (const float*)d_in[5];
    const float* bs  = (const float*)d_in[6];
    float* out = (float*)d_out;   // [0:192) scores, [192:) root_hidden (64x512)

    char* ws = (char*)d_ws;
    float*  xg  = (float*)ws;                   //   262144 B : xg_table[4][64][256]
    __bf16* BtP = (__bf16*)(ws + 262144);       //  1310720 B : packed B fragments
    __bf16* h0  = (__bf16*)(ws + 1572864);      // 33554432 B : hP ping (parent of lev9)
    __bf16* c0  = (__bf16*)(ws + 35127296);     // 33554432 B : cc ping
    __bf16* h1  = (__bf16*)(ws + 68681728);     // 16777216 B : hP pong
    __bf16* c1  = (__bf16*)(ws + 85458944);     // 16777216 B : cc pong (total 102236160)

    xg_prep<<<dim3(256), dim3(256), 0, stream>>>(emb, W, bW, xg);
    bt_prep<<<dim3(320), dim3(256), 0, stream>>>(U, BtP);
    // Leaf: 2^21 threads, packed-coalesced writes into h0/c0 (parent space 32768).
    leaf_kernel<<<dim3(8192), dim3(256), 0, stream>>>(ids, xg, h0, c0);

    __bf16* hb[2] = {h0, h1};
    __bf16* cb[2] = {c0, c1};
    int cur = 0;
    for (int lev = 9; lev >= 1; lev--) {
        int M = 64 << lev;                      // rows at this level
        int RG = (M + 255) / 256;
        float* rh = (lev == 1) ? (out + 192) : nullptr;
        level_kernel<<<dim3(RG * 16), dim3(256), 0, stream>>>(
            hb[cur], cb[cur], BtP, xg, ids, hb[1 - cur], cb[1 - cur], rh, lev, M, RG);
        cur = 1 - cur;
    }
    scores_kernel<<<dim3(64), dim3(192), 0, stream>>>(out + 192, Ws, bs, out);
}